// Round 14
// baseline (48.564 us; speedup 1.0000x reference)
//
#include <hip/hip_runtime.h>
#include <hip/hip_bf16.h>
#include <math.h>
#include <stdint.h>

#define N_RAYS    32768
#define N_SAMPLES (N_RAYS * 32)
#define THRESH 0.0001f
#define TBL_OFF  (16u * 1024u * 1024u)   // frag table after smp[] in d_ws

// record ids in frag table (one uint4 per lane per record)
#define R_A1   0   // +t (2)
#define R_A2   2   // +c (4)
#define R_R1A  6   // +2t+c (4)
#define R_R1B  10  // +t (2)
#define R_AR2  12  // +c (4)
#define R_AR2F 16  // +c (2)
#define R_B2I  18  // +i (4)
#define R_ARI  22  // +i (4)
#define NREC   26

typedef __attribute__((ext_vector_type(8)))  __bf16 bf16x8;
typedef __attribute__((ext_vector_type(16))) float  f32x16;
typedef float f4a __attribute__((ext_vector_type(4), aligned(4)));

union FragU  { __hip_bfloat162 h2[4]; uint32_t w[4]; bf16x8 v; };
union RecU   { bf16x8 v; uint4 u; };
union Rec16U { f32x16 v; uint4 u[4]; float f[16]; };

__device__ inline __hip_bfloat162 pk2(float lo, float hi) {
    float2 t; t.x = lo; t.y = hi;
    return __float22bfloat162_rn(t);
}

__device__ inline bf16x8 pack8(const float* vals) {
    FragU u;
    u.h2[0] = pk2(vals[0], vals[1]);
    u.h2[1] = pk2(vals[2], vals[3]);
    u.h2[2] = pk2(vals[4], vals[5]);
    u.h2[3] = pk2(vals[6], vals[7]);
    return u.v;
}

__device__ inline float rcp_fast(float x) {
    float r;
    asm("v_rcp_f32 %0, %1" : "=v"(r) : "v"(x));
    return r;
}
__device__ inline float sigmoid_fast(float x) { return rcp_fast(1.0f + __expf(-x)); }
__device__ inline float softplus_fast(float x) {
    const float e = __expf(-fabsf(x));
    return fmaxf(x, 0.0f) + __logf(1.0f + e);
}

template <int P>
__device__ inline bf16x8 packB_relu(f32x16 a) {
    FragU u;
    u.h2[0] = pk2(fmaxf(a[P+0],0.f), fmaxf(a[P+1],0.f));
    u.h2[1] = pk2(fmaxf(a[P+2],0.f), fmaxf(a[P+3],0.f));
    u.h2[2] = pk2(fmaxf(a[P+4],0.f), fmaxf(a[P+5],0.f));
    u.h2[3] = pk2(fmaxf(a[P+6],0.f), fmaxf(a[P+7],0.f));
    return u.v;
}
template <int P>
__device__ inline bf16x8 packB_plain(f32x16 a) {
    FragU u;
    u.h2[0] = pk2(a[P+0], a[P+1]);
    u.h2[1] = pk2(a[P+2], a[P+3]);
    u.h2[2] = pk2(a[P+4], a[P+5]);
    u.h2[3] = pk2(a[P+6], a[P+7]);
    return u.v;
}

// ---------------------------------------------------------------------------
// Setup kernel: per-lane weight fragments for the 32x32x16 path (identical to
// rounds 12/13 — layout verified). D layout: col=lane&31,
// row=(reg&3)+8*(reg>>2)+4*(lane>>5);  rr(q,h) = (q&3)+8*(q>>2)+4*h.
// ---------------------------------------------------------------------------
__global__ __launch_bounds__(256) void nerf_build_frags(
    const float* __restrict__ w1,  const float* __restrict__ b1,
    const float* __restrict__ w2,  const float* __restrict__ b2,
    const float* __restrict__ w_sigma, const float* __restrict__ b_sigma,
    const float* __restrict__ w_rgb1,  const float* __restrict__ b_rgb1,
    const float* __restrict__ w_rgb2,  const float* __restrict__ b_rgb2,
    uint4* __restrict__ tbl)
{
    const int wid  = threadIdx.x >> 6;
    const int lane = threadIdx.x & 63;
    const int m    = lane & 31;
    const int h    = lane >> 5;
    RecU rec;

    if (wid == 0) {
        #pragma unroll
        for (int t = 0; t < 2; ++t) {        // A1: rows j=32t+m; k slots h=0,q0..3
            float v[8] = {0,0,0,0,0,0,0,0};
            if (h == 0) {
                const int j = 32*t + m;
                v[0] = w1[j]; v[1] = w1[64+j]; v[2] = w1[128+j]; v[3] = b1[j];
            }
            rec.v = pack8(v); tbl[(R_A1+t)*64 + lane] = rec.u;
        }
        #pragma unroll
        for (int c = 0; c < 4; ++c) {        // A2: A[f=m][j=16c+rr(q,h)] = w2[j*32+f]
            float v[8];
            #pragma unroll
            for (int q = 0; q < 8; ++q) {
                const int j = 16*c + (q&3) + 8*(q>>2) + 4*h;
                v[q] = w2[j*32 + m];
            }
            rec.v = pack8(v); tbl[(R_A2+c)*64 + lane] = rec.u;
        }
    } else if (wid == 1) {
        #pragma unroll
        for (int t = 0; t < 2; ++t)          // Ar1a: rows j=32t+m; k=f=16c+rr
            #pragma unroll
            for (int c = 0; c < 2; ++c) {
                float v[8];
                #pragma unroll
                for (int q = 0; q < 8; ++q) {
                    const int f = 16*c + (q&3) + 8*(q>>2) + 4*h;
                    v[q] = w_rgb1[f*64 + 32*t + m];
                }
                rec.v = pack8(v); tbl[(R_R1A+2*t+c)*64 + lane] = rec.u;
            }
        #pragma unroll
        for (int t = 0; t < 2; ++t) {        // Ar1b: dirs+bias on h=1 slots q0..3
            float v[8] = {0,0,0,0,0,0,0,0};
            if (h == 1) {
                const int j = 32*t + m;
                v[0] = w_rgb1[32*64 + j]; v[1] = w_rgb1[33*64 + j];
                v[2] = w_rgb1[34*64 + j]; v[3] = b_rgb1[j];
            }
            rec.v = pack8(v); tbl[(R_R1B+t)*64 + lane] = rec.u;
        }
    } else if (wid == 2) {
        #pragma unroll
        for (int c = 0; c < 4; ++c) {        // Ar2: rows m=0..2 rgb; k=hh=16c+rr
            float v[8];
            #pragma unroll
            for (int q = 0; q < 8; ++q) {
                const int hh = 16*c + (q&3) + 8*(q>>2) + 4*h;
                v[q] = (m < 3) ? w_rgb2[hh*3 + m] : 0.0f;
            }
            rec.v = pack8(v); tbl[(R_AR2+c)*64 + lane] = rec.u;
        }
        #pragma unroll
        for (int c = 0; c < 2; ++c) {        // Ar2f: w_sigma on row m=3; k=f=16c+rr
            float v[8];
            #pragma unroll
            for (int q = 0; q < 8; ++q) {
                const int f = 16*c + (q&3) + 8*(q>>2) + 4*h;
                v[q] = (m == 3) ? w_sigma[f] : 0.0f;
            }
            rec.v = pack8(v); tbl[(R_AR2F+c)*64 + lane] = rec.u;
        }
        Rec16U r16;
        #pragma unroll
        for (int i = 0; i < 4; ++i) {        // b2i: C-init, reg=4i+e -> b2[e+8i+4h]
            #pragma unroll
            for (int e = 0; e < 4; ++e) r16.f[4*i+e] = b2[e + 8*i + 4*h];
        }
        #pragma unroll
        for (int i = 0; i < 4; ++i) tbl[(R_B2I+i)*64 + lane] = r16.u[i];
        #pragma unroll
        for (int i = 0; i < 4; ++i) {        // arinit: row r=e+8i+4h
            #pragma unroll
            for (int e = 0; e < 4; ++e) {
                const int r = e + 8*i + 4*h;
                r16.f[4*i+e] = (r < 3) ? b_rgb2[r] : ((r == 3) ? b_sigma[0] : 0.0f);
            }
        }
        #pragma unroll
        for (int i = 0; i < 4; ++i) tbl[(R_ARI+i)*64 + lane] = r16.u[i];
    }
}

// ---------------------------------------------------------------------------
// Main MFMA MLP, 32x32x16, single-stream, WEIGHTS IN LDS (shared across the
// block's 4 waves — identical for all waves; registers were the wrong home).
// M-split on layer1/rgb1 halves the transient f32x16 accumulator peak.
// Target: ~135 unified regs -> 3-4 waves/SIMD (vs the 2 that every previous
// round was silently pinned at).
// ---------------------------------------------------------------------------
__global__ __launch_bounds__(256, 3) void nerf_mlp_mfma(
    const float* __restrict__ samples,   // (N_SAMPLES, 7)
    const uint4* __restrict__ tbl,       // [26][64] frag table
    float4* __restrict__ out)            // (N_SAMPLES): tau, r, g, b
{
    __shared__ uint4 wlds[NREC * 64];    // 26.6 KB: A-frag records

    // cooperative copy of the weight-fragment table into LDS
    for (int i = threadIdx.x; i < NREC * 64; i += 256) wlds[i] = tbl[i];

    const int lane = threadIdx.x & 63;
    const int m32  = lane & 31;
    const int h    = lane >> 5;
    const int wgid = (blockIdx.x * blockDim.x + threadIdx.x) >> 6;  // 0..4095
    const int base0 = wgid * 256;        // 8 tiles x 32 samples

    // tile-0 sample loads (2-deep rotating buffers)
    f4a sa[2], sb[2];
    {
        const float* sp = samples + (size_t)(base0 + m32) * 7;
        sa[0] = *(const f4a*)sp;  sb[0] = *(const f4a*)(sp + 3);
    }

    // C-init vectors stay in registers (AGPR-able, used as MFMA C operand)
    f32x16 b2i, arinit;
    {
        Rec16U r16;
        #pragma unroll
        for (int i = 0; i < 4; ++i) r16.u[i] = tbl[(R_B2I+i)*64 + lane];
        b2i = r16.v;
        #pragma unroll
        for (int i = 0; i < 4; ++i) r16.u[i] = tbl[(R_ARI+i)*64 + lane];
        arinit = r16.v;
    }

    __syncthreads();

    // LDS fragment read: ds_read_b128 at base(lane*16) + rec*1024 (imm offset)
    const uint4* wl = &wlds[lane];
    #define LDW(rec) ({ RecU r_; r_.u = wl[(rec)*64]; r_.v; })

    const f32x16 zero16 = {0,0,0,0,0,0,0,0,0,0,0,0,0,0,0,0};

    #pragma unroll
    for (int it = 0; it < 8; ++it) {
        const int cb = it & 1;
        const int nb = (it + 1) & 1;
        if (it < 7) {
            const float* sp = samples + (size_t)(base0 + (it + 1) * 32 + m32) * 7;
            sa[nb] = *(const f4a*)sp;  sb[nb] = *(const f4a*)(sp + 3);
        }

        // merged input kstep: h=0 lanes pos+1, h=1 lanes dirs+1 (q4-7 unused)
        FragU bin;
        bin.h2[0] = pk2(h ? sb[cb].x : sa[cb].x, h ? sb[cb].y : sa[cb].y);
        bin.h2[1] = pk2(h ? sb[cb].z : sa[cb].z, 1.0f);
        bin.w[2] = 0; bin.w[3] = 0;

        // layer1, M-split into two M=32 halves (one f32x16 transient each)
        bf16x8 B2c[4];
        {
            f32x16 a0 = __builtin_amdgcn_mfma_f32_32x32x16_bf16(LDW(R_A1+0), bin.v, zero16, 0,0,0);
            B2c[0] = packB_relu<0>(a0);
            B2c[1] = packB_relu<8>(a0);
            f32x16 a1 = __builtin_amdgcn_mfma_f32_32x32x16_bf16(LDW(R_A1+1), bin.v, zero16, 0,0,0);
            B2c[2] = packB_relu<0>(a1);
            B2c[3] = packB_relu<8>(a1);
        }

        // layer2: feats = W2^T.h1 + b2 (C-init), K=64 -> 4 chained ksteps
        f32x16 acc2;
        acc2 = __builtin_amdgcn_mfma_f32_32x32x16_bf16(LDW(R_A2+0), B2c[0], b2i, 0,0,0);
        acc2 = __builtin_amdgcn_mfma_f32_32x32x16_bf16(LDW(R_A2+1), B2c[1], acc2, 0,0,0);
        acc2 = __builtin_amdgcn_mfma_f32_32x32x16_bf16(LDW(R_A2+2), B2c[2], acc2, 0,0,0);
        acc2 = __builtin_amdgcn_mfma_f32_32x32x16_bf16(LDW(R_A2+3), B2c[3], acc2, 0,0,0);
        bf16x8 Bf0 = packB_plain<0>(acc2);
        bf16x8 Bf1 = packB_plain<8>(acc2);

        // rgb1, M-split halves: h = relu(Wr1a^T.feats + Wr1b^T.[dirs;1])
        bf16x8 Bh[4];
        #pragma unroll
        for (int t = 0; t < 2; ++t) {
            f32x16 a;
            a = __builtin_amdgcn_mfma_f32_32x32x16_bf16(LDW(R_R1A+2*t+0), Bf0, zero16, 0,0,0);
            a = __builtin_amdgcn_mfma_f32_32x32x16_bf16(LDW(R_R1A+2*t+1), Bf1, a, 0,0,0);
            a = __builtin_amdgcn_mfma_f32_32x32x16_bf16(LDW(R_R1B+t),     bin.v, a, 0,0,0);
            Bh[2*t+0] = packB_relu<0>(a);
            Bh[2*t+1] = packB_relu<8>(a);
        }

        // rgb2 rows 0-2 + sigma row 3, biases via C-init
        f32x16 ar;
        ar = __builtin_amdgcn_mfma_f32_32x32x16_bf16(LDW(R_AR2+0), Bh[0], arinit, 0,0,0);
        ar = __builtin_amdgcn_mfma_f32_32x32x16_bf16(LDW(R_AR2+1), Bh[1], ar, 0,0,0);
        ar = __builtin_amdgcn_mfma_f32_32x32x16_bf16(LDW(R_AR2+2), Bh[2], ar, 0,0,0);
        ar = __builtin_amdgcn_mfma_f32_32x32x16_bf16(LDW(R_AR2+3), Bh[3], ar, 0,0,0);
        ar = __builtin_amdgcn_mfma_f32_32x32x16_bf16(LDW(R_AR2F+0), Bf0, ar, 0,0,0);
        ar = __builtin_amdgcn_mfma_f32_32x32x16_bf16(LDW(R_AR2F+1), Bf1, ar, 0,0,0);

        const float rr    = sigmoid_fast(ar[0]);
        const float gg    = sigmoid_fast(ar[1]);
        const float bb    = sigmoid_fast(ar[2]);
        const float sigma = softplus_fast(ar[3]);
        const float tau   = sigma * sb[cb].w;
        if (lane < 32) out[base0 + it * 32 + m32] = make_float4(tau, rr, gg, bb);
    }
    #undef LDW
}

// ---------------------------------------------------------------------------
// Kernel 2: one wave per ray — scan tau, gate, reduce.
// ---------------------------------------------------------------------------
__global__ __launch_bounds__(256) void nerf_render_kernel(
    const float4* __restrict__ smp,
    const int*    __restrict__ packing,
    const float*  __restrict__ bg,
    float*        __restrict__ out)
{
    const int gtid = blockIdx.x * blockDim.x + threadIdx.x;
    const int ray  = gtid >> 6;
    const int lane = threadIdx.x & 63;
    if (ray >= N_RAYS) return;

    const int start = packing[2 * ray];
    const int count = packing[2 * ray + 1];

    float tau = 0.0f, r = 0.0f, g = 0.0f, b = 0.0f;
    if (lane < count) {
        const float4 v = smp[start + lane];
        tau = v.x; r = v.y; g = v.z; b = v.w;
    }

    float incl = tau;
    #pragma unroll
    for (int off = 1; off < 64; off <<= 1) {
        const float v = __shfl_up(incl, off, 64);
        if (lane >= off) incl += v;
    }
    const float c_excl = incl - tau;

    const float T     = __expf(-c_excl);
    const float alpha = 1.0f - __expf(-tau);
    float w = (lane < count && T > THRESH) ? T * alpha : 0.0f;

    float cr = r * w, cg = g * w, cb = b * w;

    #pragma unroll
    for (int off = 32; off > 0; off >>= 1) {
        cr += __shfl_down(cr, off, 64);
        cg += __shfl_down(cg, off, 64);
        cb += __shfl_down(cb, off, 64);
        w  += __shfl_down(w,  off, 64);
    }

    if (lane == 0) {
        out[ray * 3 + 0] = cr + bg[0] * (1.0f - w);
        out[ray * 3 + 1] = cg + bg[1] * (1.0f - w);
        out[ray * 3 + 2] = cb + bg[2] * (1.0f - w);
    }
}

extern "C" void kernel_launch(void* const* d_in, const int* in_sizes, int n_in,
                              void* d_out, int out_size, void* d_ws, size_t ws_size,
                              hipStream_t stream) {
    const float* samples  = (const float*)d_in[0];
    const int*   packing  = (const int*)  d_in[1];
    const float* w1       = (const float*)d_in[3];
    const float* b1       = (const float*)d_in[4];
    const float* w2       = (const float*)d_in[5];
    const float* b2       = (const float*)d_in[6];
    const float* w_sigma  = (const float*)d_in[7];
    const float* b_sigma  = (const float*)d_in[8];
    const float* w_rgb1   = (const float*)d_in[9];
    const float* b_rgb1   = (const float*)d_in[10];
    const float* w_rgb2   = (const float*)d_in[11];
    const float* b_rgb2   = (const float*)d_in[12];
    const float* bg       = (const float*)d_in[13];

    float4* smp = (float4*)d_ws;                         // 16 MiB
    uint4*  tbl = (uint4*)((char*)d_ws + TBL_OFF);       // 26x64x16B frag table
    float*  out = (float*)d_out;

    nerf_build_frags<<<1, 256, 0, stream>>>(
        w1, b1, w2, b2, w_sigma, b_sigma,
        w_rgb1, b_rgb1, w_rgb2, b_rgb2, tbl);

    // 1024 blocks x 4 waves = 4096 waves x 8 tiles x 32 samples = N_SAMPLES
    nerf_mlp_mfma<<<1024, 256, 0, stream>>>(samples, tbl, (float4*)smp);

    nerf_render_kernel<<<(N_RAYS * 64) / 256, 256, 0, stream>>>(smp, packing, bg, out);
}